// Round 5
// baseline (1243.360 us; speedup 1.0000x reference)
//
#include <hip/hip_runtime.h>
#include <stdint.h>

// ---------- problem constants ----------
#define DD 768
#define HH 12
#define HDIM 64
#define TT 256
#define BCN 152          // B*C
#define MROWS 38912      // B*N
#define HID 3072
#define MB_CNT 152       // MROWS / 256

typedef __attribute__((ext_vector_type(8))) short bf16x8;
typedef __attribute__((ext_vector_type(4))) float f32x4;

__device__ __forceinline__ float b2f(unsigned short u) {
  union { unsigned int i; float f; } c; c.i = ((unsigned int)u) << 16; return c.f;
}
__device__ __forceinline__ unsigned short f2b(float f) {
  union { float f; unsigned int i; } c; c.f = f;
  unsigned int x = c.i;
  return (unsigned short)((x + 0x7fffu + ((x >> 16) & 1u)) >> 16);
}

__device__ __forceinline__ void gload16(const unsigned short* g, unsigned short* l) {
  __builtin_amdgcn_global_load_lds(
      (const __attribute__((address_space(1))) void*)g,
      (__attribute__((address_space(3))) void*)l, 16, 0, 0);
}

// ---------- fp32 -> bf16 weight convert ----------
__global__ __launch_bounds__(256) void k_cvt(const float* __restrict__ in,
                                             unsigned short* __restrict__ out, int n4) {
  int i = blockIdx.x * 256 + threadIdx.x;
  if (i >= n4) return;
  float4 a = ((const float4*)in)[i];
  ushort4 u;
  u.x = f2b(a.x); u.y = f2b(a.y); u.z = f2b(a.z); u.w = f2b(a.w);
  ((ushort4*)out)[i] = u;
}

// ---------- LayerNorm (fp32 in -> bf16 out), one wave per row of 768 ----------
__global__ __launch_bounds__(256) void k_ln(const float* __restrict__ x,
                                            const float* __restrict__ w,
                                            const float* __restrict__ b,
                                            unsigned short* __restrict__ out) {
  int lane = threadIdx.x & 63;
  int wv = threadIdx.x >> 6;
  size_t row = (size_t)blockIdx.x * 4 + wv;
  const float4* xr = (const float4*)(x + row * DD);
  float4 v0 = xr[lane], v1 = xr[lane + 64], v2 = xr[lane + 128];
  float s = v0.x + v0.y + v0.z + v0.w + v1.x + v1.y + v1.z + v1.w + v2.x + v2.y + v2.z + v2.w;
  float q = v0.x*v0.x + v0.y*v0.y + v0.z*v0.z + v0.w*v0.w
          + v1.x*v1.x + v1.y*v1.y + v1.z*v1.z + v1.w*v1.w
          + v2.x*v2.x + v2.y*v2.y + v2.z*v2.z + v2.w*v2.w;
#pragma unroll
  for (int m = 1; m < 64; m <<= 1) { s += __shfl_xor(s, m, 64); q += __shfl_xor(q, m, 64); }
  float mean = s * (1.0f / 768.0f);
  float var = q * (1.0f / 768.0f) - mean * mean;
  float rstd = rsqrtf(var + 1e-5f);
  ushort4* orow = (ushort4*)(out + row * DD);
#pragma unroll
  for (int i = 0; i < 3; i++) {
    int idx = lane + i * 64;
    float4 v = (i == 0) ? v0 : (i == 1) ? v1 : v2;
    float4 ww = ((const float4*)w)[idx];
    float4 bb = ((const float4*)b)[idx];
    ushort4 u;
    u.x = f2b((v.x - mean) * rstd * ww.x + bb.x);
    u.y = f2b((v.y - mean) * rstd * ww.y + bb.y);
    u.z = f2b((v.z - mean) * rstd * ww.z + bb.z);
    u.w = f2b((v.w - mean) * rstd * ww.w + bb.w);
    orow[idx] = u;
  }
}

// ---------- persistent 8-phase 256x256 GEMM, m201 wait structure ----------
// 256 blocks x 512 thr (8 waves, 2M x 4N), wave tile 128x64 (interleaved halves).
// LDS 128 KiB: 2 dbuf x (A 256x64 + B 256x64), both-sides XOR swizzle.
// Prefetch distance 7 stage-calls: t+1's Ah1 @P1; t+2 @P2-P5; t+3 @P6-P8.
// vmcnt(6) ONLY at P1/P5 (3 half-tiles in flight); one barrier per phase.
// m-major persistent strips (A-panel reuse). Epilogue overlaps staged loads.
// MODE 0: bf16 store. MODE 1: +bias +resid -> f32. MODE 2: +bias +GELU -> bf16.

template <int MH>
__device__ __forceinline__ void read_a(const unsigned short* Al, bf16x8 (&af)[4][2],
                                       int wr, int cl, int hi) {
#pragma unroll
  for (int mi = 0; mi < 4; mi++)
#pragma unroll
    for (int ks = 0; ks < 2; ks++) {
      int row = MH * 128 + wr * 64 + mi * 16 + cl;
      af[mi][ks] = *(const bf16x8*)&Al[row * 64 + (((ks * 4 + hi) ^ (row & 7)) * 8)];
    }
}

template <int G>
__device__ __forceinline__ void read_b(const unsigned short* Bl, bf16x8 (&bfr)[2][2][2],
                                       int wc, int cl, int hi) {
#pragma unroll
  for (int ni = 0; ni < 2; ni++)
#pragma unroll
    for (int ks = 0; ks < 2; ks++) {
      int row = G * 128 + wc * 32 + ni * 16 + cl;
      bfr[G][ni][ks] = *(const bf16x8*)&Bl[row * 64 + (((ks * 4 + hi) ^ (row & 7)) * 8)];
    }
}

template <int MH, int G>
__device__ __forceinline__ void mfma_q(f32x4 (&acc)[2][4][2][2], const bf16x8 (&af)[4][2],
                                       const bf16x8 (&bfr)[2][2][2]) {
  __builtin_amdgcn_s_setprio(1);
#pragma unroll
  for (int mi = 0; mi < 4; mi++)
#pragma unroll
    for (int ni = 0; ni < 2; ni++)
#pragma unroll
      for (int ks = 0; ks < 2; ks++)
        acc[MH][mi][G][ni] = __builtin_amdgcn_mfma_f32_16x16x32_bf16(
            af[mi][ks], bfr[G][ni][ks], acc[MH][mi][G][ni], 0, 0, 0);
  __builtin_amdgcn_s_setprio(0);
}

#define VM6   asm volatile("s_waitcnt vmcnt(6)" ::: "memory")
#define VM0   asm volatile("s_waitcnt vmcnt(0)" ::: "memory")
#define LGKM0 do { asm volatile("s_waitcnt lgkmcnt(0)" ::: "memory"); \
                   __builtin_amdgcn_sched_barrier(0); } while (0)
#define BAR   __builtin_amdgcn_s_barrier()

template <int MODE>
__global__ __launch_bounds__(512, 1) void k_gemm5(const unsigned short* __restrict__ A,
                                                  const unsigned short* __restrict__ W,
                                                  const float* __restrict__ bias,
                                                  const float* resid,
                                                  void* outv, int N, int K, int NB) {
  __shared__ __align__(16) unsigned short As[2][256 * 64];
  __shared__ __align__(16) unsigned short Bs[2][256 * 64];
  const int tid = threadIdx.x;
  const int lane = tid & 63, wv = tid >> 6;
  const int wr = wv >> 2, wc = wv & 3;   // 2M x 4N
  const int cl = lane & 15, hi = lane >> 4;

  // persistent split: XCD-contiguous strips of m-major tile order (A reuse)
  const int b = blockIdx.x;
  const int bp = (b & 7) * 32 + (b >> 3);
  const int ntiles = MB_CNT * NB;
  const int q = ntiles >> 8, r = ntiles & 255;
  const int t0 = bp < r ? bp * (q + 1) : r * (q + 1) + (bp - r) * q;
  const int cnt = bp < r ? q + 1 : q;

  auto stA = [&](const unsigned short* base, int kt, int bb, int h) {
#pragma unroll
    for (int j = 0; j < 2; j++) {
      int idx = j * 512 + tid;
      int row = h * 128 + (idx >> 3);
      int cg = (idx & 7) ^ (row & 7);
      gload16(base + (size_t)row * K + (size_t)kt * 64 + cg * 8,
              &As[bb][row * 64 + (idx & 7) * 8]);
    }
  };
  auto stB = [&](const unsigned short* base, int kt, int bb, int h) {
#pragma unroll
    for (int j = 0; j < 2; j++) {
      int idx = j * 512 + tid;
      int row = h * 128 + (idx >> 3);
      int cg = (idx & 7) ^ (row & 7);
      gload16(base + (size_t)row * K + (size_t)kt * 64 + cg * 8,
              &Bs[bb][row * 64 + (idx & 7) * 8]);
    }
  };

  f32x4 acc[2][4][2][2];
  bf16x8 af[4][2], bfr[2][2][2];
  const int nt = K >> 6;   // 12 or 48 (even)

  for (int i = 0; i < cnt; i++) {
    const int tau = t0 + i;
    const int m_blk = tau / NB;          // m-major: consecutive taus share m_blk
    const int n_blk = tau % NB;
    const size_t bm = (size_t)m_blk * 256, bn = (size_t)n_blk * 256;
    const unsigned short* Ab = A + bm * K;
    const unsigned short* Wb = W + bn * K;
    const bool hasNext = (i + 1 < cnt);
    const int tau2 = hasNext ? tau + 1 : tau;
    const unsigned short* An = A + (size_t)(tau2 / NB) * 256 * K;
    const unsigned short* Wn = W + (size_t)(tau2 % NB) * 256 * K;

#pragma unroll
    for (int a0 = 0; a0 < 2; a0++)
#pragma unroll
      for (int a1 = 0; a1 < 4; a1++)
#pragma unroll
        for (int a2 = 0; a2 < 2; a2++)
#pragma unroll
          for (int a3 = 0; a3 < 2; a3++) acc[a0][a1][a2][a3] = (f32x4){0.f, 0.f, 0.f, 0.f};

    if (i == 0) {
      // prologue (7 calls): kt0 {Ah0,Bh0,Bh1,Ah1} -> buf0; kt1 {Ah0,Bh0,Bh1} -> buf1
      stA(Ab, 0, 0, 0); stB(Wb, 0, 0, 0); stB(Wb, 0, 0, 1); stA(Ab, 0, 0, 1);
      stA(Ab, 1, 1, 0); stB(Wb, 1, 1, 0); stB(Wb, 1, 1, 1);
    }

    for (int t = 0; t < nt; t += 2) {
      const bool seam = (t + 2 == nt);            // t+2,t+3 live in next tile
      const bool last = seam && !hasNext;         // strip end: drain
      const unsigned short* A2 = seam ? An : Ab;
      const unsigned short* W2 = seam ? Wn : Wb;
      const int k2 = seam ? 0 : t + 2;
      const int k3 = seam ? 1 : t + 3;

      // P1: (mh0,g0) on buf0 | publish K-tile t | stage t+1's Ah1
      VM6; BAR;
      read_a<0>(As[0], af, wr, cl, hi);
      read_b<0>(Bs[0], bfr, wc, cl, hi);
      stA(Ab, t + 1, 1, 1);
      LGKM0;
      mfma_q<0, 0>(acc, af, bfr);
      // P2: (mh0,g1) | stage t+2 Ah0
      BAR;
      read_b<1>(Bs[0], bfr, wc, cl, hi);
      if (!last) stA(A2, k2, 0, 0);
      LGKM0;
      mfma_q<0, 1>(acc, af, bfr);
      // P3: (mh1,g0) | stage t+2 Bh0
      BAR;
      read_a<1>(As[0], af, wr, cl, hi);
      if (!last) stB(W2, k2, 0, 0);
      LGKM0;
      mfma_q<1, 0>(acc, af, bfr);
      // P4: (mh1,g1) | stage t+2 Bh1
      BAR;
      if (!last) stB(W2, k2, 0, 1);
      mfma_q<1, 1>(acc, af, bfr);

      // P5: (mh0,g0) on buf1 | publish K-tile t+1 | stage t+2 Ah1
      if (last) { VM0; } else { VM6; }
      BAR;
      read_a<0>(As[1], af, wr, cl, hi);
      read_b<0>(Bs[1], bfr, wc, cl, hi);
      if (!last) stA(A2, k2, 0, 1);
      LGKM0;
      mfma_q<0, 0>(acc, af, bfr);
      // P6: (mh0,g1) | stage t+3 Ah0
      BAR;
      read_b<1>(Bs[1], bfr, wc, cl, hi);
      if (!last) stA(A2, k3, 1, 0);
      LGKM0;
      mfma_q<0, 1>(acc, af, bfr);
      // P7: (mh1,g0) | stage t+3 Bh0
      BAR;
      read_a<1>(As[1], af, wr, cl, hi);
      if (!last) stB(W2, k3, 1, 0);
      LGKM0;
      mfma_q<1, 0>(acc, af, bfr);
      // P8: (mh1,g1) | stage t+3 Bh1
      BAR;
      if (!last) stB(W2, k3, 1, 1);
      mfma_q<1, 1>(acc, af, bfr);
    }

    // epilogue for tile tau (staged loads for next tile keep flying)
#pragma unroll
    for (int mh = 0; mh < 2; mh++)
#pragma unroll
      for (int mi = 0; mi < 4; mi++)
#pragma unroll
        for (int g = 0; g < 2; g++)
#pragma unroll
          for (int ni = 0; ni < 2; ni++) {
            size_t col = bn + g * 128 + wc * 32 + ni * 16 + cl;
#pragma unroll
            for (int rr = 0; rr < 4; rr++) {
              size_t row = bm + mh * 128 + wr * 64 + mi * 16 + hi * 4 + rr;
              float v = acc[mh][mi][g][ni][rr];
              if (MODE == 0) {
                ((unsigned short*)outv)[row * N + col] = f2b(v);
              } else if (MODE == 1) {
                v += bias[col] + resid[row * N + col];
                ((float*)outv)[row * N + col] = v;
              } else {
                v += bias[col];
                float gg = 0.5f * v * (1.0f + erff(v * 0.70710678118654752f));
                ((unsigned short*)outv)[row * N + col] = f2b(gg);
              }
            }
          }
  }
}

// ---------- attention: one block per (head, bc); 4 waves x 64 Q rows ----------
__global__ __launch_bounds__(256) void k_attn(const unsigned short* __restrict__ qkv,
                                              unsigned short* __restrict__ o) {
  __shared__ unsigned short Kc[64 * 64];
  __shared__ unsigned short Vt[64 * 64];
  __shared__ unsigned short Pl[4][64 * 64];
  int h = blockIdx.x;
  int bc = blockIdx.y;
  int tid = threadIdx.x;
  int lane = tid & 63, wv = tid >> 6;
  int cl = lane & 15, hi = lane >> 4;

  bf16x8 qf[4][2];
#pragma unroll
  for (int m = 0; m < 4; m++)
#pragma unroll
    for (int ks = 0; ks < 2; ks++) {
      size_t row = (size_t)bc * 256 + wv * 64 + m * 16 + cl;
      bf16x8 raw = *(const bf16x8*)(qkv + row * 2304 + h * 64 + ks * 32 + hi * 8);
      bf16x8 sc;
#pragma unroll
      for (int j = 0; j < 8; j++) sc[j] = (short)f2b(0.125f * b2f((unsigned short)raw[j]));
      qf[m][ks] = sc;
    }

  f32x4 oacc[4][4];
#pragma unroll
  for (int m = 0; m < 4; m++)
#pragma unroll
    for (int n = 0; n < 4; n++) oacc[m][n] = (f32x4){0.f, 0.f, 0.f, 0.f};
  float mrun[4][4], lrun[4][4];
#pragma unroll
  for (int m = 0; m < 4; m++)
#pragma unroll
    for (int r = 0; r < 4; r++) { mrun[m][r] = -1e30f; lrun[m][r] = 0.f; }

  for (int j = 0; j < 4; j++) {
    __syncthreads();
#pragma unroll
    for (int it = 0; it < 2; ++it) {
      int idx = it * 256 + tid;
      int tok = idx >> 3;
      int c8 = idx & 7;
      size_t gtok = (size_t)bc * 256 + j * 64 + tok;
      uint4 kvv = *(const uint4*)(qkv + gtok * 2304 + 768 + h * 64 + c8 * 8);
      *(uint4*)&Kc[tok * 64 + c8 * 8] = kvv;
      union { uint4 u4; unsigned short us[8]; } cv;
      cv.u4 = *(const uint4*)(qkv + gtok * 2304 + 1536 + h * 64 + c8 * 8);
#pragma unroll
      for (int jj = 0; jj < 8; jj++) Vt[(c8 * 8 + jj) * 64 + tok] = cv.us[jj];
    }
    __syncthreads();

    f32x4 s[4][4];
#pragma unroll
    for (int m = 0; m < 4; m++)
#pragma unroll
      for (int n = 0; n < 4; n++) s[m][n] = (f32x4){0.f, 0.f, 0.f, 0.f};
#pragma unroll
    for (int ks = 0; ks < 2; ++ks) {
      int ko = ks * 32 + hi * 8;
      bf16x8 kf[4];
#pragma unroll
      for (int n = 0; n < 4; n++) kf[n] = *(const bf16x8*)&Kc[(n * 16 + cl) * 64 + ko];
#pragma unroll
      for (int m = 0; m < 4; m++)
#pragma unroll
        for (int n = 0; n < 4; n++)
          s[m][n] = __builtin_amdgcn_mfma_f32_16x16x32_bf16(qf[m][ks], kf[n], s[m][n], 0, 0, 0);
    }

#pragma unroll
    for (int m = 0; m < 4; m++) {
#pragma unroll
      for (int r = 0; r < 4; r++) {
        float pm = fmaxf(fmaxf(s[m][0][r], s[m][1][r]), fmaxf(s[m][2][r], s[m][3][r]));
#pragma unroll
        for (int xm = 1; xm < 16; xm <<= 1) pm = fmaxf(pm, __shfl_xor(pm, xm, 64));
        float nm = fmaxf(mrun[m][r], pm);
        float fac = __expf(mrun[m][r] - nm);
        mrun[m][r] = nm;
        float ps = 0.f;
#pragma unroll
        for (int n = 0; n < 4; n++) {
          float e = __expf(s[m][n][r] - nm);
          s[m][n][r] = e;
          ps += e;
        }
#pragma unroll
        for (int xm = 1; xm < 16; xm <<= 1) ps += __shfl_xor(ps, xm, 64);
        lrun[m][r] = lrun[m][r] * fac + ps;
#pragma unroll
        for (int n2 = 0; n2 < 4; n2++) oacc[m][n2][r] *= fac;
      }
#pragma unroll
      for (int n = 0; n < 4; n++)
#pragma unroll
        for (int r = 0; r < 4; r++)
          Pl[wv][(m * 16 + hi * 4 + r) * 64 + n * 16 + cl] = f2b(s[m][n][r]);
    }
    __syncthreads();

#pragma unroll
    for (int ks = 0; ks < 2; ++ks) {
      int ko = ks * 32 + hi * 8;
      bf16x8 pa[4], pv[4];
#pragma unroll
      for (int m = 0; m < 4; m++) pa[m] = *(const bf16x8*)&Pl[wv][(m * 16 + cl) * 64 + ko];
#pragma unroll
      for (int n = 0; n < 4; n++) pv[n] = *(const bf16x8*)&Vt[(n * 16 + cl) * 64 + ko];
#pragma unroll
      for (int m = 0; m < 4; m++)
#pragma unroll
        for (int n = 0; n < 4; n++)
          oacc[m][n] = __builtin_amdgcn_mfma_f32_16x16x32_bf16(pa[m], pv[n], oacc[m][n], 0, 0, 0);
    }
  }

#pragma unroll
  for (int m = 0; m < 4; m++)
#pragma unroll
    for (int r = 0; r < 4; r++) {
      float inv = 1.0f / lrun[m][r];
      size_t row = (size_t)bc * 256 + wv * 64 + m * 16 + hi * 4 + r;
#pragma unroll
      for (int n = 0; n < 4; n++)
        o[row * DD + h * 64 + n * 16 + cl] = f2b(oacc[m][n][r] * inv);
    }
}

extern "C" void kernel_launch(void* const* d_in, const int* in_sizes, int n_in,
                              void* d_out, int out_size, void* d_ws, size_t ws_size,
                              hipStream_t stream) {
  const float* x     = (const float*)d_in[0];
  const float* n1w   = (const float*)d_in[1];
  const float* n1b   = (const float*)d_in[2];
  const float* qkvw  = (const float*)d_in[3];
  const float* projw = (const float*)d_in[4];
  const float* projb = (const float*)d_in[5];
  const float* n2w   = (const float*)d_in[6];
  const float* n2b   = (const float*)d_in[7];
  const float* fc1w  = (const float*)d_in[8];
  const float* fc1b  = (const float*)d_in[9];
  const float* fc2w  = (const float*)d_in[10];
  const float* fc2b  = (const float*)d_in[11];
  float* out = (float*)d_out;

  const size_t NEED = 312999936ull;
  if (ws_size < NEED) return;
  char* ws = (char*)d_ws;
  unsigned short* h   = (unsigned short*)(ws);
  unsigned short* qkv = (unsigned short*)(ws + 59768832ull);
  unsigned short* ob  = (unsigned short*)(ws + 239075328ull);
  unsigned short* act = (unsigned short*)(ws + 59768832ull);
  unsigned short* wq  = (unsigned short*)(ws + 298844160ull);
  unsigned short* wp  = wq + 2304 * 768;
  unsigned short* w1  = wp + 768 * 768;
  unsigned short* w2  = w1 + 3072 * 768;

  // convert weights to bf16
  k_cvt<<<1728, 256, 0, stream>>>(qkvw, wq, 2304 * 768 / 4);
  k_cvt<<<576, 256, 0, stream>>>(projw, wp, 768 * 768 / 4);
  k_cvt<<<2304, 256, 0, stream>>>(fc1w, w1, 3072 * 768 / 4);
  k_cvt<<<2304, 256, 0, stream>>>(fc2w, w2, 768 * 3072 / 4);

  // LN1
  k_ln<<<MROWS / 4, 256, 0, stream>>>(x, n1w, n1b, h);
  // QKV: (38912x768) @ (2304x768)^T -> bf16 (NB = 9)
  k_gemm5<0><<<256, 512, 0, stream>>>(h, wq, nullptr, nullptr, qkv, 2304, 768, 9);
  // attention
  k_attn<<<dim3(HH, BCN), 256, 0, stream>>>(qkv, ob);
  // proj + bias + residual(x) -> y in d_out (fp32)  (NB = 3)
  k_gemm5<1><<<256, 512, 0, stream>>>(ob, wp, projb, x, out, 768, 768, 3);
  // LN2 on y
  k_ln<<<MROWS / 4, 256, 0, stream>>>(out, n2w, n2b, h);
  // FC1 + bias + exact GELU -> bf16 act (NB = 12)
  k_gemm5<2><<<256, 512, 0, stream>>>(h, w1, fc1b, nullptr, act, 3072, 768, 12);
  // FC2 + bias + residual(y) -> d_out (fp32) (NB = 3, K = 3072)
  k_gemm5<1><<<256, 512, 0, stream>>>(act, w2, fc2b, out, out, 768, 3072, 3);
}

// Round 6
// 1137.323 us; speedup vs baseline: 1.0932x; 1.0932x over previous
//
#include <hip/hip_runtime.h>
#include <stdint.h>

// ---------- problem constants ----------
#define DD 768
#define HH 12
#define HDIM 64
#define TT 256
#define BCN 152          // B*C
#define MROWS 38912      // B*N
#define HID 3072

typedef __attribute__((ext_vector_type(8))) short bf16x8;
typedef __attribute__((ext_vector_type(4))) float f32x4;

__device__ __forceinline__ float b2f(unsigned short u) {
  union { unsigned int i; float f; } c; c.i = ((unsigned int)u) << 16; return c.f;
}
__device__ __forceinline__ unsigned short f2b(float f) {
  union { float f; unsigned int i; } c; c.f = f;
  unsigned int x = c.i;
  return (unsigned short)((x + 0x7fffu + ((x >> 16) & 1u)) >> 16);
}

__device__ __forceinline__ void gload16(const unsigned short* g, unsigned short* l) {
  __builtin_amdgcn_global_load_lds(
      (const __attribute__((address_space(1))) void*)g,
      (__attribute__((address_space(3))) void*)l, 16, 0, 0);
}

// ---------- fp32 -> bf16 weight convert ----------
__global__ __launch_bounds__(256) void k_cvt(const float* __restrict__ in,
                                             unsigned short* __restrict__ out, int n4) {
  int i = blockIdx.x * 256 + threadIdx.x;
  if (i >= n4) return;
  float4 a = ((const float4*)in)[i];
  ushort4 u;
  u.x = f2b(a.x); u.y = f2b(a.y); u.z = f2b(a.z); u.w = f2b(a.w);
  ((ushort4*)out)[i] = u;
}

// ---------- LayerNorm (fp32 in -> bf16 out), one wave per row of 768 ----------
__global__ __launch_bounds__(256) void k_ln(const float* __restrict__ x,
                                            const float* __restrict__ w,
                                            const float* __restrict__ b,
                                            unsigned short* __restrict__ out) {
  int lane = threadIdx.x & 63;
  int wv = threadIdx.x >> 6;
  size_t row = (size_t)blockIdx.x * 4 + wv;
  const float4* xr = (const float4*)(x + row * DD);
  float4 v0 = xr[lane], v1 = xr[lane + 64], v2 = xr[lane + 128];
  float s = v0.x + v0.y + v0.z + v0.w + v1.x + v1.y + v1.z + v1.w + v2.x + v2.y + v2.z + v2.w;
  float q = v0.x*v0.x + v0.y*v0.y + v0.z*v0.z + v0.w*v0.w
          + v1.x*v1.x + v1.y*v1.y + v1.z*v1.z + v1.w*v1.w
          + v2.x*v2.x + v2.y*v2.y + v2.z*v2.z + v2.w*v2.w;
#pragma unroll
  for (int m = 1; m < 64; m <<= 1) { s += __shfl_xor(s, m, 64); q += __shfl_xor(q, m, 64); }
  float mean = s * (1.0f / 768.0f);
  float var = q * (1.0f / 768.0f) - mean * mean;
  float rstd = rsqrtf(var + 1e-5f);
  ushort4* orow = (ushort4*)(out + row * DD);
#pragma unroll
  for (int i = 0; i < 3; i++) {
    int idx = lane + i * 64;
    float4 v = (i == 0) ? v0 : (i == 1) ? v1 : v2;
    float4 ww = ((const float4*)w)[idx];
    float4 bb = ((const float4*)b)[idx];
    ushort4 u;
    u.x = f2b((v.x - mean) * rstd * ww.x + bb.x);
    u.y = f2b((v.y - mean) * rstd * ww.y + bb.y);
    u.z = f2b((v.z - mean) * rstd * ww.z + bb.z);
    u.w = f2b((v.w - mean) * rstd * ww.w + bb.w);
    orow[idx] = u;
  }
}

// ---------- m97-structure GEMM + T2 swizzle: out[M,N] = A[M,K] @ W[N,K]^T ----------
// BM=BN=128, BK=64, 256 thr = 4 waves (2x2), wave quadrant 64x64, acc 4x4.
// Single-buffered 32 KiB LDS -> 4 blocks/CU (implicit cross-block MFMA/stage
// overlap, m114). Both-sides XOR swizzle on 16B granules (conflict-free reads).
// MODE 0: bf16 store. MODE 1: +bias +resid -> f32. MODE 2: +bias +GELU -> bf16.
template <int MODE>
__global__ __launch_bounds__(256, 4) void k_gemm6(const unsigned short* __restrict__ A,
                                                  const unsigned short* __restrict__ W,
                                                  const float* __restrict__ bias,
                                                  const float* resid,
                                                  void* outv, int N, int K) {
  __shared__ __align__(16) unsigned short As[128 * 64];
  __shared__ __align__(16) unsigned short Bs[128 * 64];
  const int tid = threadIdx.x;
  const int lane = tid & 63, wv = tid >> 6;
  const int wr = wv >> 1, wc = wv & 1;
  const int cl = lane & 15, hi = lane >> 4;

  // T1 bijective XCD swizzle (nwg % 8 == 0 for all our grids)
  const int nbx = gridDim.x;
  const int nwg = nbx * gridDim.y;
  const int flat = blockIdx.y * nbx + blockIdx.x;
  const int swz = (flat & 7) * (nwg >> 3) + (flat >> 3);
  const size_t bm = (size_t)(swz / nbx) * 128;
  const size_t bn = (size_t)(swz % nbx) * 128;
  const unsigned short* Ab = A + bm * K;
  const unsigned short* Wb = W + bn * K;

  f32x4 acc[4][4];
#pragma unroll
  for (int m = 0; m < 4; m++)
#pragma unroll
    for (int n = 0; n < 4; n++) acc[m][n] = (f32x4){0.f, 0.f, 0.f, 0.f};

  const int nk = K >> 6;
  for (int kt = 0; kt < nk; ++kt) {
    __syncthreads();   // previous iteration's reads complete before overwrite
#pragma unroll
    for (int i = 0; i < 4; i++) {
      int g = i * 256 + tid;            // granule id, linear in lane
      int row = g >> 3;
      int cg = (g & 7) ^ (row & 7);     // inverse-swizzled global source
      gload16(Ab + (size_t)row * K + (size_t)kt * 64 + cg * 8, &As[g * 8]);
      gload16(Wb + (size_t)row * K + (size_t)kt * 64 + cg * 8, &Bs[g * 8]);
    }
    __syncthreads();   // compiler drains vmcnt(0) before barrier -> tile visible
#pragma unroll
    for (int ks = 0; ks < 2; ++ks) {
      bf16x8 af[4], bfr[4];
#pragma unroll
      for (int m = 0; m < 4; m++) {
        int row = wr * 64 + m * 16 + cl;
        af[m] = *(const bf16x8*)&As[row * 64 + (((ks * 4 + hi) ^ (row & 7)) * 8)];
      }
#pragma unroll
      for (int n = 0; n < 4; n++) {
        int row = wc * 64 + n * 16 + cl;
        bfr[n] = *(const bf16x8*)&Bs[row * 64 + (((ks * 4 + hi) ^ (row & 7)) * 8)];
      }
#pragma unroll
      for (int m = 0; m < 4; m++)
#pragma unroll
        for (int n = 0; n < 4; n++)
          acc[m][n] = __builtin_amdgcn_mfma_f32_16x16x32_bf16(af[m], bfr[n], acc[m][n], 0, 0, 0);
    }
  }

#pragma unroll
  for (int m = 0; m < 4; m++) {
#pragma unroll
    for (int n = 0; n < 4; n++) {
      size_t col = bn + wc * 64 + n * 16 + cl;
#pragma unroll
      for (int r = 0; r < 4; r++) {
        size_t row = bm + wr * 64 + m * 16 + hi * 4 + r;
        float v = acc[m][n][r];
        if (MODE == 0) {
          ((unsigned short*)outv)[row * N + col] = f2b(v);
        } else if (MODE == 1) {
          v += bias[col] + resid[row * N + col];
          ((float*)outv)[row * N + col] = v;
        } else {
          v += bias[col];
          float g = 0.5f * v * (1.0f + erff(v * 0.70710678118654752f));
          ((unsigned short*)outv)[row * N + col] = f2b(g);
        }
      }
    }
  }
}

// ---------- attention: one block per (head, bc); 4 waves x 64 Q rows ----------
__global__ __launch_bounds__(256) void k_attn(const unsigned short* __restrict__ qkv,
                                              unsigned short* __restrict__ o) {
  __shared__ unsigned short Kc[64 * 64];
  __shared__ unsigned short Vt[64 * 64];
  __shared__ unsigned short Pl[4][64 * 64];
  int h = blockIdx.x;
  int bc = blockIdx.y;
  int tid = threadIdx.x;
  int lane = tid & 63, wv = tid >> 6;
  int cl = lane & 15, hi = lane >> 4;

  bf16x8 qf[4][2];
#pragma unroll
  for (int m = 0; m < 4; m++)
#pragma unroll
    for (int ks = 0; ks < 2; ks++) {
      size_t row = (size_t)bc * 256 + wv * 64 + m * 16 + cl;
      bf16x8 raw = *(const bf16x8*)(qkv + row * 2304 + h * 64 + ks * 32 + hi * 8);
      bf16x8 sc;
#pragma unroll
      for (int j = 0; j < 8; j++) sc[j] = (short)f2b(0.125f * b2f((unsigned short)raw[j]));
      qf[m][ks] = sc;
    }

  f32x4 oacc[4][4];
#pragma unroll
  for (int m = 0; m < 4; m++)
#pragma unroll
    for (int n = 0; n < 4; n++) oacc[m][n] = (f32x4){0.f, 0.f, 0.f, 0.f};
  float mrun[4][4], lrun[4][4];
#pragma unroll
  for (int m = 0; m < 4; m++)
#pragma unroll
    for (int r = 0; r < 4; r++) { mrun[m][r] = -1e30f; lrun[m][r] = 0.f; }

  for (int j = 0; j < 4; j++) {
    __syncthreads();
#pragma unroll
    for (int it = 0; it < 2; ++it) {
      int idx = it * 256 + tid;
      int tok = idx >> 3;
      int c8 = idx & 7;
      size_t gtok = (size_t)bc * 256 + j * 64 + tok;
      uint4 kvv = *(const uint4*)(qkv + gtok * 2304 + 768 + h * 64 + c8 * 8);
      *(uint4*)&Kc[tok * 64 + c8 * 8] = kvv;
      union { uint4 u4; unsigned short us[8]; } cv;
      cv.u4 = *(const uint4*)(qkv + gtok * 2304 + 1536 + h * 64 + c8 * 8);
#pragma unroll
      for (int jj = 0; jj < 8; jj++) Vt[(c8 * 8 + jj) * 64 + tok] = cv.us[jj];
    }
    __syncthreads();

    f32x4 s[4][4];
#pragma unroll
    for (int m = 0; m < 4; m++)
#pragma unroll
      for (int n = 0; n < 4; n++) s[m][n] = (f32x4){0.f, 0.f, 0.f, 0.f};
#pragma unroll
    for (int ks = 0; ks < 2; ++ks) {
      int ko = ks * 32 + hi * 8;
      bf16x8 kf[4];
#pragma unroll
      for (int n = 0; n < 4; n++) kf[n] = *(const bf16x8*)&Kc[(n * 16 + cl) * 64 + ko];
#pragma unroll
      for (int m = 0; m < 4; m++)
#pragma unroll
        for (int n = 0; n < 4; n++)
          s[m][n] = __builtin_amdgcn_mfma_f32_16x16x32_bf16(qf[m][ks], kf[n], s[m][n], 0, 0, 0);
    }

#pragma unroll
    for (int m = 0; m < 4; m++) {
#pragma unroll
      for (int r = 0; r < 4; r++) {
        float pm = fmaxf(fmaxf(s[m][0][r], s[m][1][r]), fmaxf(s[m][2][r], s[m][3][r]));
#pragma unroll
        for (int xm = 1; xm < 16; xm <<= 1) pm = fmaxf(pm, __shfl_xor(pm, xm, 64));
        float nm = fmaxf(mrun[m][r], pm);
        float fac = __expf(mrun[m][r] - nm);
        mrun[m][r] = nm;
        float ps = 0.f;
#pragma unroll
        for (int n = 0; n < 4; n++) {
          float e = __expf(s[m][n][r] - nm);
          s[m][n][r] = e;
          ps += e;
        }
#pragma unroll
        for (int xm = 1; xm < 16; xm <<= 1) ps += __shfl_xor(ps, xm, 64);
        lrun[m][r] = lrun[m][r] * fac + ps;
#pragma unroll
        for (int n2 = 0; n2 < 4; n2++) oacc[m][n2][r] *= fac;
      }
#pragma unroll
      for (int n = 0; n < 4; n++)
#pragma unroll
        for (int r = 0; r < 4; r++)
          Pl[wv][(m * 16 + hi * 4 + r) * 64 + n * 16 + cl] = f2b(s[m][n][r]);
    }
    __syncthreads();

#pragma unroll
    for (int ks = 0; ks < 2; ++ks) {
      int ko = ks * 32 + hi * 8;
      bf16x8 pa[4], pv[4];
#pragma unroll
      for (int m = 0; m < 4; m++) pa[m] = *(const bf16x8*)&Pl[wv][(m * 16 + cl) * 64 + ko];
#pragma unroll
      for (int n = 0; n < 4; n++) pv[n] = *(const bf16x8*)&Vt[(n * 16 + cl) * 64 + ko];
#pragma unroll
      for (int m = 0; m < 4; m++)
#pragma unroll
        for (int n = 0; n < 4; n++)
          oacc[m][n] = __builtin_amdgcn_mfma_f32_16x16x32_bf16(pa[m], pv[n], oacc[m][n], 0, 0, 0);
    }
  }

#pragma unroll
  for (int m = 0; m < 4; m++)
#pragma unroll
    for (int r = 0; r < 4; r++) {
      float inv = 1.0f / lrun[m][r];
      size_t row = (size_t)bc * 256 + wv * 64 + m * 16 + hi * 4 + r;
#pragma unroll
      for (int n = 0; n < 4; n++)
        o[row * DD + h * 64 + n * 16 + cl] = f2b(oacc[m][n][r] * inv);
    }
}

extern "C" void kernel_launch(void* const* d_in, const int* in_sizes, int n_in,
                              void* d_out, int out_size, void* d_ws, size_t ws_size,
                              hipStream_t stream) {
  const float* x     = (const float*)d_in[0];
  const float* n1w   = (const float*)d_in[1];
  const float* n1b   = (const float*)d_in[2];
  const float* qkvw  = (const float*)d_in[3];
  const float* projw = (const float*)d_in[4];
  const float* projb = (const float*)d_in[5];
  const float* n2w   = (const float*)d_in[6];
  const float* n2b   = (const float*)d_in[7];
  const float* fc1w  = (const float*)d_in[8];
  const float* fc1b  = (const float*)d_in[9];
  const float* fc2w  = (const float*)d_in[10];
  const float* fc2b  = (const float*)d_in[11];
  float* out = (float*)d_out;

  const size_t NEED = 312999936ull;
  if (ws_size < NEED) return;
  char* ws = (char*)d_ws;
  unsigned short* h   = (unsigned short*)(ws);
  unsigned short* qkv = (unsigned short*)(ws + 59768832ull);
  unsigned short* ob  = (unsigned short*)(ws + 239075328ull);
  unsigned short* act = (unsigned short*)(ws + 59768832ull);
  unsigned short* wq  = (unsigned short*)(ws + 298844160ull);
  unsigned short* wp  = wq + 2304 * 768;
  unsigned short* w1  = wp + 768 * 768;
  unsigned short* w2  = w1 + 3072 * 768;

  // convert weights to bf16
  k_cvt<<<1728, 256, 0, stream>>>(qkvw, wq, 2304 * 768 / 4);
  k_cvt<<<576, 256, 0, stream>>>(projw, wp, 768 * 768 / 4);
  k_cvt<<<2304, 256, 0, stream>>>(fc1w, w1, 3072 * 768 / 4);
  k_cvt<<<2304, 256, 0, stream>>>(fc2w, w2, 768 * 3072 / 4);

  // LN1
  k_ln<<<MROWS / 4, 256, 0, stream>>>(x, n1w, n1b, h);
  // QKV: (38912x768) @ (2304x768)^T -> bf16
  k_gemm6<0><<<dim3(2304 / 128, MROWS / 128), 256, 0, stream>>>(h, wq, nullptr, nullptr, qkv, 2304, 768);
  // attention
  k_attn<<<dim3(HH, BCN), 256, 0, stream>>>(qkv, ob);
  // proj + bias + residual(x) -> y in d_out (fp32)
  k_gemm6<1><<<dim3(768 / 128, MROWS / 128), 256, 0, stream>>>(ob, wp, projb, x, out, 768, 768);
  // LN2 on y
  k_ln<<<MROWS / 4, 256, 0, stream>>>(out, n2w, n2b, h);
  // FC1 + bias + exact GELU -> bf16 act
  k_gemm6<2><<<dim3(3072 / 128, MROWS / 128), 256, 0, stream>>>(h, w1, fc1b, nullptr, act, 3072, 768);
  // FC2 + bias + residual(y) -> d_out (fp32)
  k_gemm6<1><<<dim3(768 / 128, MROWS / 128), 256, 0, stream>>>(act, w2, fc2b, out, out, 768, 3072);
}

// Round 7
// 1012.329 us; speedup vs baseline: 1.2282x; 1.1235x over previous
//
#include <hip/hip_runtime.h>
#include <stdint.h>

// ---------- problem constants ----------
#define DD 768
#define HH 12
#define HDIM 64
#define TT 256
#define BCN 152          // B*C
#define MROWS 38912      // B*N
#define HID 3072

typedef __attribute__((ext_vector_type(8))) short bf16x8;
typedef __attribute__((ext_vector_type(4))) float f32x4;

__device__ __forceinline__ float b2f(unsigned short u) {
  union { unsigned int i; float f; } c; c.i = ((unsigned int)u) << 16; return c.f;
}
__device__ __forceinline__ unsigned short f2b(float f) {
  union { float f; unsigned int i; } c; c.f = f;
  unsigned int x = c.i;
  return (unsigned short)((x + 0x7fffu + ((x >> 16) & 1u)) >> 16);
}

__device__ __forceinline__ void gload16(const unsigned short* g, unsigned short* l) {
  __builtin_amdgcn_global_load_lds(
      (const __attribute__((address_space(1))) void*)g,
      (__attribute__((address_space(3))) void*)l, 16, 0, 0);
}

// ---------- fp32 -> bf16 weight convert ----------
__global__ __launch_bounds__(256) void k_cvt(const float* __restrict__ in,
                                             unsigned short* __restrict__ out, int n4) {
  int i = blockIdx.x * 256 + threadIdx.x;
  if (i >= n4) return;
  float4 a = ((const float4*)in)[i];
  ushort4 u;
  u.x = f2b(a.x); u.y = f2b(a.y); u.z = f2b(a.z); u.w = f2b(a.w);
  ((ushort4*)out)[i] = u;
}

// ---------- LayerNorm (fp32 in -> bf16 out), one wave per row of 768 ----------
__global__ __launch_bounds__(256) void k_ln(const float* __restrict__ x,
                                            const float* __restrict__ w,
                                            const float* __restrict__ b,
                                            unsigned short* __restrict__ out) {
  int lane = threadIdx.x & 63;
  int wv = threadIdx.x >> 6;
  size_t row = (size_t)blockIdx.x * 4 + wv;
  const float4* xr = (const float4*)(x + row * DD);
  float4 v0 = xr[lane], v1 = xr[lane + 64], v2 = xr[lane + 128];
  float s = v0.x + v0.y + v0.z + v0.w + v1.x + v1.y + v1.z + v1.w + v2.x + v2.y + v2.z + v2.w;
  float q = v0.x*v0.x + v0.y*v0.y + v0.z*v0.z + v0.w*v0.w
          + v1.x*v1.x + v1.y*v1.y + v1.z*v1.z + v1.w*v1.w
          + v2.x*v2.x + v2.y*v2.y + v2.z*v2.z + v2.w*v2.w;
#pragma unroll
  for (int m = 1; m < 64; m <<= 1) { s += __shfl_xor(s, m, 64); q += __shfl_xor(q, m, 64); }
  float mean = s * (1.0f / 768.0f);
  float var = q * (1.0f / 768.0f) - mean * mean;
  float rstd = rsqrtf(var + 1e-5f);
  ushort4* orow = (ushort4*)(out + row * DD);
#pragma unroll
  for (int i = 0; i < 3; i++) {
    int idx = lane + i * 64;
    float4 v = (i == 0) ? v0 : (i == 1) ? v1 : v2;
    float4 ww = ((const float4*)w)[idx];
    float4 bb = ((const float4*)b)[idx];
    ushort4 u;
    u.x = f2b((v.x - mean) * rstd * ww.x + bb.x);
    u.y = f2b((v.y - mean) * rstd * ww.y + bb.y);
    u.z = f2b((v.z - mean) * rstd * ww.z + bb.z);
    u.w = f2b((v.w - mean) * rstd * ww.w + bb.w);
    orow[idx] = u;
  }
}

// ---------- m97-structure GEMM + T2 swizzle: out[M,N] = A[M,K] @ W[N,K]^T ----------
// BM=BN=128, BK=64, 256 thr = 4 waves (2x2), wave quadrant 64x64, acc 4x4.
// Single-buffered 32 KiB LDS -> 4 blocks/CU (implicit cross-block MFMA/stage
// overlap, m114). Both-sides XOR swizzle on 16B granules (conflict-free reads).
// MODE 0: bf16 store. MODE 1: +bias +resid -> f32. MODE 2: +bias +GELU -> bf16.
template <int MODE>
__global__ __launch_bounds__(256, 4) void k_gemm6(const unsigned short* __restrict__ A,
                                                  const unsigned short* __restrict__ W,
                                                  const float* __restrict__ bias,
                                                  const float* resid,
                                                  void* outv, int N, int K) {
  __shared__ __align__(16) unsigned short As[128 * 64];
  __shared__ __align__(16) unsigned short Bs[128 * 64];
  const int tid = threadIdx.x;
  const int lane = tid & 63, wv = tid >> 6;
  const int wr = wv >> 1, wc = wv & 1;
  const int cl = lane & 15, hi = lane >> 4;

  // T1 bijective XCD swizzle (nwg % 8 == 0 for all our grids)
  const int nbx = gridDim.x;
  const int nwg = nbx * gridDim.y;
  const int flat = blockIdx.y * nbx + blockIdx.x;
  const int swz = (flat & 7) * (nwg >> 3) + (flat >> 3);
  const size_t bm = (size_t)(swz / nbx) * 128;
  const size_t bn = (size_t)(swz % nbx) * 128;
  const unsigned short* Ab = A + bm * K;
  const unsigned short* Wb = W + bn * K;

  f32x4 acc[4][4];
#pragma unroll
  for (int m = 0; m < 4; m++)
#pragma unroll
    for (int n = 0; n < 4; n++) acc[m][n] = (f32x4){0.f, 0.f, 0.f, 0.f};

  const int nk = K >> 6;
  for (int kt = 0; kt < nk; ++kt) {
    __syncthreads();   // previous iteration's reads complete before overwrite
#pragma unroll
    for (int i = 0; i < 4; i++) {
      int g = i * 256 + tid;            // granule id, linear in lane
      int row = g >> 3;
      int cg = (g & 7) ^ (row & 7);     // inverse-swizzled global source
      gload16(Ab + (size_t)row * K + (size_t)kt * 64 + cg * 8, &As[g * 8]);
      gload16(Wb + (size_t)row * K + (size_t)kt * 64 + cg * 8, &Bs[g * 8]);
    }
    __syncthreads();   // compiler drains vmcnt(0) before barrier -> tile visible
#pragma unroll
    for (int ks = 0; ks < 2; ++ks) {
      bf16x8 af[4], bfr[4];
#pragma unroll
      for (int m = 0; m < 4; m++) {
        int row = wr * 64 + m * 16 + cl;
        af[m] = *(const bf16x8*)&As[row * 64 + (((ks * 4 + hi) ^ (row & 7)) * 8)];
      }
#pragma unroll
      for (int n = 0; n < 4; n++) {
        int row = wc * 64 + n * 16 + cl;
        bfr[n] = *(const bf16x8*)&Bs[row * 64 + (((ks * 4 + hi) ^ (row & 7)) * 8)];
      }
#pragma unroll
      for (int m = 0; m < 4; m++)
#pragma unroll
        for (int n = 0; n < 4; n++)
          acc[m][n] = __builtin_amdgcn_mfma_f32_16x16x32_bf16(af[m], bfr[n], acc[m][n], 0, 0, 0);
    }
  }

#pragma unroll
  for (int m = 0; m < 4; m++) {
#pragma unroll
    for (int n = 0; n < 4; n++) {
      size_t col = bn + wc * 64 + n * 16 + cl;
#pragma unroll
      for (int r = 0; r < 4; r++) {
        size_t row = bm + wr * 64 + m * 16 + hi * 4 + r;
        float v = acc[m][n][r];
        if (MODE == 0) {
          ((unsigned short*)outv)[row * N + col] = f2b(v);
        } else if (MODE == 1) {
          v += bias[col] + resid[row * N + col];
          ((float*)outv)[row * N + col] = v;
        } else {
          v += bias[col];
          float g = 0.5f * v * (1.0f + erff(v * 0.70710678118654752f));
          ((unsigned short*)outv)[row * N + col] = f2b(g);
        }
      }
    }
  }
}

// ---------- attention v2: one block per (head, bc); 8 waves x 32 Q rows ----------
// K: gload16 staging (linear dest, inverse-swizzled src) + swizzled ds_read_b128
//    (conflict-free, GEMM-verified pattern), double-buffered, prefetched.
// V: reg-staged (prefetch j+1 before softmax), transposed scalar LDS write with
//    double-XOR granule swizzle (writes 2-way=free, reads conflict-free).
// P: per-wave 16x64 LDS slab, same swizzle (conflict-free pa reads).
// 2 barriers per j-chunk; LDS 40 KiB.
__global__ __launch_bounds__(512) void k_attn(const unsigned short* __restrict__ qkv,
                                              unsigned short* __restrict__ o) {
  __shared__ __align__(16) unsigned short Kc[2][64 * 64];   // 16 KiB
  __shared__ __align__(16) unsigned short Vt[64 * 64];      // 8 KiB
  __shared__ __align__(16) unsigned short Pl[8][16 * 64];   // 16 KiB
  const int h = blockIdx.x, bc = blockIdx.y;
  const int tid = threadIdx.x;
  const int lane = tid & 63, wv = tid >> 6;    // 8 waves
  const int cl = lane & 15, hi = lane >> 4;

  // Q fragments for this wave's 32 rows, scaled by 0.125 (exact in bf16)
  bf16x8 qf[2][2];
#pragma unroll
  for (int m = 0; m < 2; m++)
#pragma unroll
    for (int ks = 0; ks < 2; ks++) {
      size_t row = (size_t)bc * 256 + wv * 32 + m * 16 + cl;
      bf16x8 raw = *(const bf16x8*)(qkv + row * 2304 + h * 64 + ks * 32 + hi * 8);
      bf16x8 sc;
#pragma unroll
      for (int jx = 0; jx < 8; jx++) sc[jx] = (short)f2b(0.125f * b2f((unsigned short)raw[jx]));
      qf[m][ks] = sc;
    }

  f32x4 oacc[2][4];
#pragma unroll
  for (int m = 0; m < 2; m++)
#pragma unroll
    for (int n = 0; n < 4; n++) oacc[m][n] = (f32x4){0.f, 0.f, 0.f, 0.f};
  float mrun[2][4], lrun[2][4];
#pragma unroll
  for (int m = 0; m < 2; m++)
#pragma unroll
    for (int r = 0; r < 4; r++) { mrun[m][r] = -1e30f; lrun[m][r] = 0.f; }

  // K staging: 512 granules, 1 per thread; linear LDS dest, pre-swizzled source
  auto stageK = [&](int j, int buf) {
    int tok = tid >> 3, c8 = tid & 7;
    size_t gtok = (size_t)bc * 256 + j * 64 + tok;
    gload16(qkv + gtok * 2304 + 768 + h * 64 + ((c8 ^ (tok & 7)) * 8), &Kc[buf][tid * 8]);
  };
  // V prefetch to regs: 1 uint4 (8 bf16 of one token) per thread
  uint4 vreg[2];
  auto loadV = [&](int j, int slot) {
    int tok = tid >> 3, c8 = tid & 7;
    size_t gtok = (size_t)bc * 256 + j * 64 + tok;
    vreg[slot] = *(const uint4*)(qkv + gtok * 2304 + 1536 + h * 64 + c8 * 8);
  };
  // V transposed write with double-XOR swizzle: element (tok,d) at
  // d*64 + ((tok>>3 ^ (d&7) ^ (d>>3)) & 7)*8 + (tok&7)
  auto writeV = [&](int slot) {
    int tok = tid >> 3, c8 = tid & 7;
    union { uint4 u4; unsigned short us[8]; } cv; cv.u4 = vreg[slot];
#pragma unroll
    for (int jj = 0; jj < 8; jj++) {
      int d = c8 * 8 + jj;
      int g = ((tok >> 3) ^ (d & 7) ^ ((d >> 3) & 7)) & 7;
      Vt[d * 64 + g * 8 + (tok & 7)] = cv.us[jj];
    }
  };

  stageK(0, 0);
  loadV(0, 0);

  for (int j = 0; j < 4; j++) {
    __syncthreads();   // drains vm+lgkm: Kc[j&1] published, vreg[j&1] ready

    // ---- S = Q K^T ----
    f32x4 s[2][4];
#pragma unroll
    for (int m = 0; m < 2; m++)
#pragma unroll
      for (int n = 0; n < 4; n++) s[m][n] = (f32x4){0.f, 0.f, 0.f, 0.f};
#pragma unroll
    for (int ks = 0; ks < 2; ++ks) {
      bf16x8 kf[4];
#pragma unroll
      for (int n = 0; n < 4; n++) {
        int row = n * 16 + cl;
        kf[n] = *(const bf16x8*)&Kc[j & 1][row * 64 + (((ks * 4 + hi) ^ (row & 7)) * 8)];
      }
#pragma unroll
      for (int m = 0; m < 2; m++)
#pragma unroll
        for (int n = 0; n < 4; n++)
          s[m][n] = __builtin_amdgcn_mfma_f32_16x16x32_bf16(qf[m][ks], kf[n], s[m][n], 0, 0, 0);
    }

    // prefetch next K and V (latency hidden under softmax; drained at next barrier)
    stageK((j + 1) & 3, (j + 1) & 1);
    loadV((j + 1) & 3, (j + 1) & 1);

    // ---- online softmax (rows = m*16 + hi*4 + r, reduce over n regs + 16 cl lanes) ----
#pragma unroll
    for (int m = 0; m < 2; m++) {
#pragma unroll
      for (int r = 0; r < 4; r++) {
        float pm = fmaxf(fmaxf(s[m][0][r], s[m][1][r]), fmaxf(s[m][2][r], s[m][3][r]));
#pragma unroll
        for (int xm = 1; xm < 16; xm <<= 1) pm = fmaxf(pm, __shfl_xor(pm, xm, 64));
        float nm = fmaxf(mrun[m][r], pm);
        float fac = __expf(mrun[m][r] - nm);
        mrun[m][r] = nm;
        float ps = 0.f;
#pragma unroll
        for (int n = 0; n < 4; n++) {
          float e = __expf(s[m][n][r] - nm);
          s[m][n][r] = e;
          ps += e;
        }
#pragma unroll
        for (int xm = 1; xm < 16; xm <<= 1) ps += __shfl_xor(ps, xm, 64);
        lrun[m][r] = lrun[m][r] * fac + ps;
#pragma unroll
        for (int n2 = 0; n2 < 4; n2++) oacc[m][n2][r] *= fac;
      }
    }

    // ---- V into LDS (transposed+swizzled), publish ----
    writeV(j & 1);
    __syncthreads();   // drains writeV ds_writes + prefetches; Vt published

    // ---- O += P V ----
    bf16x8 pv[2][4];
#pragma unroll
    for (int ks = 0; ks < 2; ks++)
#pragma unroll
      for (int n = 0; n < 4; n++) {
        int d = n * 16 + cl;
        pv[ks][n] = *(const bf16x8*)&Vt[d * 64 + ((((ks * 4 + hi) ^ (d & 7) ^ ((d >> 3) & 7)) & 7) * 8)];
      }
#pragma unroll
    for (int m = 0; m < 2; m++) {
      // P slab (wave-private, swizzled): element (q=hi*4+r, key=n*16+cl)
#pragma unroll
      for (int n = 0; n < 4; n++)
#pragma unroll
        for (int r = 0; r < 4; r++) {
          int q = hi * 4 + r;
          int g = ((n * 2 + (cl >> 3)) ^ (q & 7) ^ (q >> 3)) & 7;
          Pl[wv][q * 64 + g * 8 + (cl & 7)] = f2b(s[m][n][r]);
        }
      asm volatile("s_waitcnt lgkmcnt(0)" ::: "memory");
      __builtin_amdgcn_sched_barrier(0);
      bf16x8 pa0 = *(const bf16x8*)&Pl[wv][cl * 64 + (((hi ^ (cl & 7) ^ (cl >> 3)) & 7) * 8)];
      bf16x8 pa1 = *(const bf16x8*)&Pl[wv][cl * 64 + ((((4 + hi) ^ (cl & 7) ^ (cl >> 3)) & 7) * 8)];
#pragma unroll
      for (int n = 0; n < 4; n++)
        oacc[m][n] = __builtin_amdgcn_mfma_f32_16x16x32_bf16(pa0, pv[0][n], oacc[m][n], 0, 0, 0);
#pragma unroll
      for (int n = 0; n < 4; n++)
        oacc[m][n] = __builtin_amdgcn_mfma_f32_16x16x32_bf16(pa1, pv[1][n], oacc[m][n], 0, 0, 0);
    }
  }

  // epilogue: divide by l, store bf16 at (token, h*64+d)
#pragma unroll
  for (int m = 0; m < 2; m++)
#pragma unroll
    for (int r = 0; r < 4; r++) {
      float inv = 1.0f / lrun[m][r];
      size_t row = (size_t)bc * 256 + wv * 32 + m * 16 + hi * 4 + r;
#pragma unroll
      for (int n = 0; n < 4; n++)
        o[row * DD + h * 64 + n * 16 + cl] = f2b(oacc[m][n][r] * inv);
    }
}

extern "C" void kernel_launch(void* const* d_in, const int* in_sizes, int n_in,
                              void* d_out, int out_size, void* d_ws, size_t ws_size,
                              hipStream_t stream) {
  const float* x     = (const float*)d_in[0];
  const float* n1w   = (const float*)d_in[1];
  const float* n1b   = (const float*)d_in[2];
  const float* qkvw  = (const float*)d_in[3];
  const float* projw = (const float*)d_in[4];
  const float* projb = (const float*)d_in[5];
  const float* n2w   = (const float*)d_in[6];
  const float* n2b   = (const float*)d_in[7];
  const float* fc1w  = (const float*)d_in[8];
  const float* fc1b  = (const float*)d_in[9];
  const float* fc2w  = (const float*)d_in[10];
  const float* fc2b  = (const float*)d_in[11];
  float* out = (float*)d_out;

  const size_t NEED = 312999936ull;
  if (ws_size < NEED) return;
  char* ws = (char*)d_ws;
  unsigned short* h   = (unsigned short*)(ws);
  unsigned short* qkv = (unsigned short*)(ws + 59768832ull);
  unsigned short* ob  = (unsigned short*)(ws + 239075328ull);
  unsigned short* act = (unsigned short*)(ws + 59768832ull);
  unsigned short* wq  = (unsigned short*)(ws + 298844160ull);
  unsigned short* wp  = wq + 2304 * 768;
  unsigned short* w1  = wp + 768 * 768;
  unsigned short* w2  = w1 + 3072 * 768;

  // convert weights to bf16
  k_cvt<<<1728, 256, 0, stream>>>(qkvw, wq, 2304 * 768 / 4);
  k_cvt<<<576, 256, 0, stream>>>(projw, wp, 768 * 768 / 4);
  k_cvt<<<2304, 256, 0, stream>>>(fc1w, w1, 3072 * 768 / 4);
  k_cvt<<<2304, 256, 0, stream>>>(fc2w, w2, 768 * 3072 / 4);

  // LN1
  k_ln<<<MROWS / 4, 256, 0, stream>>>(x, n1w, n1b, h);
  // QKV: (38912x768) @ (2304x768)^T -> bf16
  k_gemm6<0><<<dim3(2304 / 128, MROWS / 128), 256, 0, stream>>>(h, wq, nullptr, nullptr, qkv, 2304, 768);
  // attention
  k_attn<<<dim3(HH, BCN), 512, 0, stream>>>(qkv, ob);
  // proj + bias + residual(x) -> y in d_out (fp32)
  k_gemm6<1><<<dim3(768 / 128, MROWS / 128), 256, 0, stream>>>(ob, wp, projb, x, out, 768, 768);
  // LN2 on y
  k_ln<<<MROWS / 4, 256, 0, stream>>>(out, n2w, n2b, h);
  // FC1 + bias + exact GELU -> bf16 act
  k_gemm6<2><<<dim3(3072 / 128, MROWS / 128), 256, 0, stream>>>(h, w1, fc1b, nullptr, act, 3072, 768);
  // FC2 + bias + residual(y) -> d_out (fp32)
  k_gemm6<1><<<dim3(768 / 128, MROWS / 128), 256, 0, stream>>>(act, w2, fc2b, out, out, 768, 3072);
}